// Round 11
// baseline (528.455 us; speedup 1.0000x reference)
//
#include <hip/hip_runtime.h>
#include <string.h>

// Conformer encoder layer, MI355X gfx950 — ROUND 11: fusion round.
// R10: 447 us; flash 46.5 (grid-limited). This round: (1) qkv GEMM epilogue
// writes QU/QV/KH head-major + compact Vbuf directly (repack_qkv_k deleted,
// ~36 MB saved); (2) pw1 GEMM fuses GLU (glu_k deleted, ~16 MB saved);
// (3) W2 GEMMs (N=512,K=2048) -> 128-tile kernel (halves A re-read traffic).
// T=1024 B=4 E=512 H=8 D=64 DFF=2048 K=31. Workspace: 93 MB.

#define T_ 1024
#define B_ 4
#define E_ 512
#define H_ 8
#define DFF_ 2048
#define KW_ 31

typedef unsigned short u16;
typedef unsigned int u32;
typedef __bf16 bf16x8 __attribute__((ext_vector_type(8)));
typedef float floatx4 __attribute__((ext_vector_type(4)));

__device__ __forceinline__ float b2f(u16 u) {
    return __uint_as_float(((u32)u) << 16);
}
__device__ __forceinline__ u16 f2b(float f) {
    u32 i = __float_as_uint(f);
    u32 r = (i + 0x7fffu + ((i >> 16) & 1u)) >> 16;  // RNE, finite inputs only
    return (u16)r;
}

__device__ __forceinline__ void glds16(const u16 *g, u16 *l) {
    __builtin_amdgcn_global_load_lds((const __attribute__((address_space(1))) void *)g,
                                     (__attribute__((address_space(3))) void *)l, 16, 0, 0);
}

// ---------------- diagnostic fill (f32 out) ---------------------------------------
__global__ __launch_bounds__(256) void fill_k(float *out, long long n, float val) {
    long long g = (long long)blockIdx.x * 256 + threadIdx.x;
    if (g < n) out[g] = val;
}

// ---------------- input dtype detect + convert ------------------------------------
__global__ __launch_bounds__(256) void detect_k(const u16 *src16, int *flag) {
    __shared__ int sh[256];
    int tid = threadIdx.x;
    int cnt = 0;
    for (int i = tid; i < 4096; i += 256) {
        u16 x = src16[2 * i];
        int e = (x >> 7) & 0xFF;
        cnt += (e == 0 || (e >= 0x70 && e <= 0x8F)) ? 1 : 0;
    }
    sh[tid] = cnt;
    __syncthreads();
    for (int s = 128; s; s >>= 1) {
        if (tid < s) sh[tid] += sh[tid + s];
        __syncthreads();
    }
    if (tid == 0) *flag = (sh[0] < 2048) ? 1 : 0;  // 1 = f32 inputs, 0 = bf16
}

struct CVT {
    const void *in[24];
    long long pre[25];
};

__global__ __launch_bounds__(256) void convert_k(CVT c, u16 *dst, const int *flag,
                                                 long long total) {
    long long g = (long long)blockIdx.x * 256 + threadIdx.x;
    if (g >= total) return;
    int s = 0;
#pragma unroll
    for (int i = 1; i < 25; i++) s += (g >= c.pre[i]) ? 1 : 0;
    long long l = g - c.pre[s];
    int f = *flag;
    u16 v = f ? f2b(((const float *)c.in[s])[l]) : ((const u16 *)c.in[s])[l];
    dst[g] = v;
}

// ---------------- generic NT GEMM: C(M,N) = A(M,K) @ B(N,K)^T ----------------------
struct GP {
    const u16 *A, *B;
    u16 *C;
    const u16 *bias;
    const void *resin;     // mode 2: residual input (bf16 or f32)
    float *xr;             // mode 2: f32 residual out
    u16 *xb;               // mode 2: bf16 copy out (may be null)
    const u16 *u2, *v2;    // mode 4: pos_bias_u / pos_bias_v (flat h*64+d)
    u16 *qu, *qv, *kh, *vb;  // mode 4: outputs
    int M, N, K, lda, ldb, ldc, mode, qcols, resin_f32;
    float qscale;
};

// 64x64 tile, BK=64, glds16 + XOR swizzle.
// modes: 0 bf16 store; 1 DoubleSwish store; 2 residual (f32+bf16); 3 GLU
// (second B tile at rows +512, ch = a*sigmoid(g))
__global__ __launch_bounds__(256) void gemm_nt(GP p) {
    __shared__ __align__(16) u16 As[64 * 64];
    __shared__ __align__(16) u16 Bs[64 * 64];
    __shared__ __align__(16) u16 Bs2[64 * 64];  // mode 3 only
    const int tid = threadIdx.x;
    const int wv = tid >> 6, ln = tid & 63;
    const int l16 = ln & 15, quad = ln >> 4;
    const int m0 = blockIdx.y * 64, n0 = blockIdx.x * 64;
    const bool glu = (p.mode == 3);
    floatx4 zero = {0.f, 0.f, 0.f, 0.f};
    floatx4 acc[4], acc2[4];
#pragma unroll
    for (int i = 0; i < 4; i++) { acc[i] = zero; acc2[i] = zero; }

    for (int k0 = 0; k0 < p.K; k0 += 64) {
        __syncthreads();
#pragma unroll
        for (int ps = 0; ps < 2; ps++) {
            int g = ps * 256 + tid;
            int row = g >> 3;
            int src = ((g & 7) ^ (row & 7)) << 3;
            if (m0 + row < p.M)
                glds16(p.A + (long long)(m0 + row) * p.lda + k0 + src, As + g * 8);
            glds16(p.B + (long long)(n0 + row) * p.ldb + k0 + src, Bs + g * 8);
            if (glu)
                glds16(p.B + (long long)(n0 + row + 512) * p.ldb + k0 + src, Bs2 + g * 8);
        }
        __syncthreads();
#pragma unroll
        for (int kk = 0; kk < 2; kk++) {
            const int swz = ((((kk << 2) | quad) ^ (l16 & 7)) << 3);
            bf16x8 af = __builtin_bit_cast(bf16x8,
                *(const uint4 *)&As[(((wv << 4) | l16) << 6) + swz]);
#pragma unroll
            for (int nt = 0; nt < 4; nt++) {
                bf16x8 bf = __builtin_bit_cast(bf16x8,
                    *(const uint4 *)&Bs[(((nt << 4) | l16) << 6) + swz]);
                acc[nt] = __builtin_amdgcn_mfma_f32_16x16x32_bf16(af, bf, acc[nt], 0, 0, 0);
            }
            if (glu) {
#pragma unroll
                for (int nt = 0; nt < 4; nt++) {
                    bf16x8 bf = __builtin_bit_cast(bf16x8,
                        *(const uint4 *)&Bs2[(((nt << 4) | l16) << 6) + swz]);
                    acc2[nt] = __builtin_amdgcn_mfma_f32_16x16x32_bf16(af, bf, acc2[nt], 0, 0, 0);
                }
            }
        }
    }

#pragma unroll
    for (int nt = 0; nt < 4; nt++) {
#pragma unroll
        for (int r = 0; r < 4; r++) {
            int gr = m0 + (wv << 4) + (quad << 2) + r;
            int gc = n0 + (nt << 4) + l16;
            if (gr >= p.M) continue;
            float y = acc[nt][r];
            if (p.bias) y += b2f(p.bias[gc]);
            if (gc < p.qcols) y *= p.qscale;
            if (p.mode == 0) {
                p.C[(long long)gr * p.ldc + gc] = f2b(y);
            } else if (p.mode == 1) {
                float s = 1.f / (1.f + __expf(1.f - y));  // x*sigmoid(x-1)
                p.C[(long long)gr * p.ldc + gc] = f2b(y * s);
            } else if (p.mode == 2) {
                long long idx = (long long)gr * p.ldc + gc;
                float rv = p.resin_f32 ? ((const float *)p.resin)[idx]
                                       : b2f(((const u16 *)p.resin)[idx]);
                float o = rv + y;
                p.xr[idx] = o;
                if (p.xb) p.xb[idx] = f2b(o);
            } else {  // mode 3: GLU -> ch
                float g2 = acc2[nt][r] + b2f(p.bias[gc + 512]);
                p.C[(long long)gr * p.ldc + gc] = f2b(y * (1.f / (1.f + __expf(-g2))));
            }
        }
    }
}

// ---------------- 128x128 GEMM (z=1, M%128==0, N%128==0, K%32==0) ------------------
// modes: 0/1/2 as above; 4 = qkv repack epilogue (q->QU/QV head-major + u/v,
// k->KH head-major, v->compact Vbuf).
__global__ __launch_bounds__(256) void gemm_nt128(GP p) {
    __shared__ __align__(16) u16 As[128 * 32];
    __shared__ __align__(16) u16 Bs[128 * 32];
    const int tid = threadIdx.x;
    const int wv = tid >> 6, ln = tid & 63;
    const int l16 = ln & 15, quad = ln >> 4;
    const int wm = (wv >> 1) << 6, wn = (wv & 1) << 6;
    const int m0 = blockIdx.y << 7, n0 = blockIdx.x << 7;
    const int srow = ln >> 2;
    const int scol = (((ln & 3) ^ ((ln >> 3) & 3)) << 3);
    const u16 *Ag1 = p.A + (long long)(m0 + (wv << 4) + srow) * p.lda + scol;
    const u16 *Ag2 = Ag1 + (long long)64 * p.lda;
    const u16 *Bg1 = p.B + (long long)(n0 + (wv << 4) + srow) * p.ldb + scol;
    const u16 *Bg2 = Bg1 + (long long)64 * p.ldb;
    u16 *Al1 = &As[(wv << 4) << 5];
    u16 *Al2 = &As[((wv << 4) + 64) << 5];
    u16 *Bl1 = &Bs[(wv << 4) << 5];
    u16 *Bl2 = &Bs[((wv << 4) + 64) << 5];
    floatx4 zero = {0.f, 0.f, 0.f, 0.f};
    floatx4 acc[4][4];
#pragma unroll
    for (int i = 0; i < 4; i++)
#pragma unroll
        for (int j = 0; j < 4; j++) acc[i][j] = zero;

    const int rswz = ((quad ^ ((l16 >> 1) & 3)) << 3);

    for (int k0 = 0; k0 < p.K; k0 += 32) {
        __syncthreads();
        glds16(Ag1 + k0, Al1);
        glds16(Ag2 + k0, Al2);
        glds16(Bg1 + k0, Bl1);
        glds16(Bg2 + k0, Bl2);
        __syncthreads();
        bf16x8 av[4], bv[4];
#pragma unroll
        for (int mt = 0; mt < 4; mt++)
            av[mt] = __builtin_bit_cast(bf16x8,
                *(const uint4 *)&As[((wm + (mt << 4) + l16) << 5) + rswz]);
#pragma unroll
        for (int nt = 0; nt < 4; nt++)
            bv[nt] = __builtin_bit_cast(bf16x8,
                *(const uint4 *)&Bs[((wn + (nt << 4) + l16) << 5) + rswz]);
#pragma unroll
        for (int mt = 0; mt < 4; mt++)
#pragma unroll
            for (int nt = 0; nt < 4; nt++)
                acc[mt][nt] = __builtin_amdgcn_mfma_f32_16x16x32_bf16(av[mt], bv[nt],
                                                                      acc[mt][nt], 0, 0, 0);
    }

#pragma unroll
    for (int mt = 0; mt < 4; mt++)
#pragma unroll
        for (int nt = 0; nt < 4; nt++)
#pragma unroll
            for (int r = 0; r < 4; r++) {
                int gr = m0 + wm + (mt << 4) + (quad << 2) + r;
                int gc = n0 + wn + (nt << 4) + l16;
                float y = acc[mt][nt][r];
                if (p.bias) y += b2f(p.bias[gc]);
                if (gc < p.qcols) y *= p.qscale;
                if (p.mode == 0) {
                    p.C[(long long)gr * p.ldc + gc] = f2b(y);
                } else if (p.mode == 1) {
                    float s = 1.f / (1.f + __expf(1.f - y));
                    p.C[(long long)gr * p.ldc + gc] = f2b(y * s);
                } else if (p.mode == 2) {
                    long long idx = (long long)gr * p.ldc + gc;
                    float rv = p.resin_f32 ? ((const float *)p.resin)[idx]
                                           : b2f(((const u16 *)p.resin)[idx]);
                    float o = rv + y;
                    p.xr[idx] = o;
                    if (p.xb) p.xb[idx] = f2b(o);
                } else {  // mode 4: qkv repack
                    int t = gr >> 2, bb = gr & 3;
                    if (gc < 512) {
                        int h = gc >> 6, d = gc & 63;
                        long long o = (((long long)(bb * 8 + h)) << 16) + (t << 6) + d;
                        float q = y * 0.125f;  // D^-0.5
                        p.qu[o] = f2b(q + b2f(p.u2[gc]));
                        p.qv[o] = f2b(q + b2f(p.v2[gc]));
                    } else if (gc < 1024) {
                        int h = (gc >> 6) & 7, d = gc & 63;
                        long long o = (((long long)(bb * 8 + h)) << 16) + (t << 6) + d;
                        p.kh[o] = f2b(y);
                    } else {
                        p.vb[(long long)gr * 512 + (gc - 1024)] = f2b(y);
                    }
                }
            }
}

// ---------------- flash attention v2 (unchanged from R10) --------------------------
struct FK {
    const u16 *QU, *QV, *KH, *PPH, *VT;
    u16 *attno;
};

__global__ __launch_bounds__(256) void flash_k(FK p) {
    __shared__ __align__(16) u16 lds[20992];  // 41 KB
    u16 *Kh = lds;            // 64 x 64 (swizzled granules)
    u16 *Ph = lds + 4096;     // 128 x 64 (swizzled)
    u16 *Vt = lds + 12288;    // 64 x 64 (swizzled)
    u16 *Pb = lds + 16384;    // 64 x 72 (padded)

    const int tid = threadIdx.x;
    const int wv = tid >> 6, ln = tid & 63;
    const int l16 = ln & 15, quad = ln >> 4;
    const int zg = blockIdx.y;
    const int i0 = blockIdx.x << 6;
    const u16 *kh0 = p.KH + (long long)zg * 65536;
    const u16 *ph0 = p.PPH + (long long)(zg & 7) * 131072;
    const u16 *vt0 = p.VT + (long long)zg * 65536;

    const long long qoff = (long long)zg * 65536 + (long long)(i0 + (wv << 4) + l16) * 64 + (quad << 3);
    bf16x8 aqu[2], aqv[2];
#pragma unroll
    for (int kk = 0; kk < 2; kk++) {
        aqu[kk] = __builtin_bit_cast(bf16x8, *(const uint4 *)(p.QU + qoff + (kk << 5)));
        aqv[kk] = __builtin_bit_cast(bf16x8, *(const uint4 *)(p.QV + qoff + (kk << 5)));
    }

    float lacc[4];
    floatx4 accO[4];
    floatx4 zero = {0.f, 0.f, 0.f, 0.f};
#pragma unroll
    for (int e = 0; e < 4; e++) lacc[e] = 0.f;
#pragma unroll
    for (int i = 0; i < 4; i++) accO[i] = zero;

    const int r16q = quad << 2;

    for (int jt = 0; jt < 16; jt++) {
        const int j0 = jt << 6;
        const int m_start = 960 - i0 + j0;
        __syncthreads();
#pragma unroll
        for (int ps = 0; ps < 2; ps++) {
            int g = ps * 256 + tid;
            int row = g >> 3;
            int src = ((g & 7) ^ (row & 7)) << 3;
            glds16(kh0 + ((j0 + row) << 6) + src, Kh + g * 8);
            glds16(vt0 + (row << 10) + j0 + src, Vt + g * 8);
        }
#pragma unroll
        for (int ps = 0; ps < 4; ps++) {
            int g = ps * 256 + tid;
            int row = g >> 3;
            int src = ((g & 7) ^ (row & 7)) << 3;
            glds16(ph0 + ((m_start + row) << 6) + src, Ph + g * 8);
        }
        __syncthreads();

        floatx4 aS[4], aB[5];
#pragma unroll
        for (int i = 0; i < 4; i++) aS[i] = zero;
#pragma unroll
        for (int i = 0; i < 5; i++) aB[i] = zero;
#pragma unroll
        for (int kk = 0; kk < 2; kk++) {
            const int swz = ((((kk << 2) | quad) ^ (l16 & 7)) << 3);
#pragma unroll
            for (int nt = 0; nt < 4; nt++) {
                bf16x8 bf = __builtin_bit_cast(bf16x8,
                    *(const uint4 *)&Kh[(((nt << 4) | l16) << 6) + swz]);
                aS[nt] = __builtin_amdgcn_mfma_f32_16x16x32_bf16(aqu[kk], bf, aS[nt], 0, 0, 0);
            }
#pragma unroll
            for (int rt = 0; rt < 5; rt++) {
                bf16x8 bf = __builtin_bit_cast(bf16x8,
                    *(const uint4 *)&Ph[((((rt + 3 - wv) << 4) | l16) << 6) + swz]);
                aB[rt] = __builtin_amdgcn_mfma_f32_16x16x32_bf16(aqv[kk], bf, aB[rt], 0, 0, 0);
            }
        }

#pragma unroll
        for (int e = 0; e < 4; e++) {
            const int r16 = r16q + e;
            const int t = l16 + 15 - r16;
            const int srcl = (quad << 4) | (t & 15);
            const int carry = t >> 4;
            float ps = 0.f;
#pragma unroll
            for (int nt = 0; nt < 4; nt++) {
                float vlo = __shfl(aB[nt][e], srcl, 64);
                float vhi = __shfl(aB[nt + 1][e], srcl, 64);
                float bd = carry ? vhi : vlo;
                float pe = __expf(aS[nt][e] + bd);
                ps += pe;
                Pb[(((wv << 4) + r16) * 72) + (nt << 4) + l16] = f2b(pe);
            }
            lacc[e] += ps;
        }

#pragma unroll
        for (int kk = 0; kk < 2; kk++) {
            const int swz = ((((kk << 2) | quad) ^ (l16 & 7)) << 3);
            bf16x8 ap = __builtin_bit_cast(bf16x8,
                *(const uint4 *)&Pb[(((wv << 4) | l16) * 72) + (kk << 5) + (quad << 3)]);
#pragma unroll
            for (int nd = 0; nd < 4; nd++) {
                bf16x8 bv = __builtin_bit_cast(bf16x8,
                    *(const uint4 *)&Vt[(((nd << 4) | l16) << 6) + swz]);
                accO[nd] = __builtin_amdgcn_mfma_f32_16x16x32_bf16(ap, bv, accO[nd], 0, 0, 0);
            }
        }
    }

    const int b = zg >> 3, h = zg & 7;
#pragma unroll
    for (int e = 0; e < 4; e++) {
#pragma unroll
        for (int msk = 1; msk < 16; msk <<= 1) lacc[e] += __shfl_xor(lacc[e], msk, 64);
        float inv = 1.f / lacc[e];
        int t = i0 + (wv << 4) + (quad << 2) + e;
#pragma unroll
        for (int nd = 0; nd < 4; nd++) {
            int d = (nd << 4) + l16;
            p.attno[(long long)(t * B_ + b) * E_ + h * 64 + d] = f2b(accO[nd][e] * inv);
        }
    }
}

// ---------------- small helper kernels -------------------------------------------

__global__ __launch_bounds__(256) void repack_pos_k(const u16 *pp, u16 *pph) {
    int gid = blockIdx.x * 256 + threadIdx.x;  // 8*2048*64 = 1M
    int h = gid >> 17, rem = gid & 131071;
    int m = rem >> 6, d = rem & 63;
    pph[gid] = (m < 2 * T_ - 1) ? pp[(long long)m * E_ + h * 64 + d] : (u16)0;
}

// Vbuf (t*4+b, h*64+d) -> VT (z, d, t)
__global__ __launch_bounds__(256) void transpose_v_k(const u16 *vb, u16 *VT) {
    __shared__ u16 lds[64 * 65];
    int z = blockIdx.y, t0 = blockIdx.x * 64;
    int b = z >> 3, h = z & 7;
    int tid = threadIdx.x, wv = tid >> 6, ln = tid & 63;
    for (int rr = 0; rr < 16; rr++) {
        int tl = wv * 16 + rr;
        lds[ln * 65 + tl] = vb[(long long)((t0 + tl) * B_ + b) * 512 + h * 64 + ln];
    }
    __syncthreads();
    int d = tid >> 2, seg = tid & 3;
    long long ob = (long long)(z * 64 + d) * T_ + t0 + seg * 16;
    for (int ii = 0; ii < 16; ii++) VT[ob + ii] = lds[d * 65 + seg * 16 + ii];
}

// depthwise conv — register sliding window. Thread = (b, channel-pair) x 8 t's.
__global__ __launch_bounds__(256) void dwconv_k(const u16 *ch, const u16 *w, const u16 *bias,
                                                u16 *cd) {
    const int cp = threadIdx.x;
    const int b = blockIdx.x >> 7;
    const int t0 = (blockIdx.x & 127) << 3;
    const int c0 = cp << 1;
    float in0[38], in1[38];
#pragma unroll
    for (int j = 0; j < 38; j++) {
        int tt = t0 - 15 + j;
        u32 v = 0;
        if (tt >= 0 && tt < T_) v = *(const u32 *)&ch[tt * 2048 + b * 512 + c0];
        in0[j] = b2f((u16)(v & 0xffff));
        in1[j] = b2f((u16)(v >> 16));
    }
    float w0[KW_], w1[KW_];
#pragma unroll
    for (int kk = 0; kk < KW_; kk++) {
        w0[kk] = b2f(w[c0 * KW_ + kk]);
        w1[kk] = b2f(w[c0 * KW_ + KW_ + kk]);
    }
    float bi0 = b2f(bias[c0]), bi1 = b2f(bias[c0 + 1]);
#pragma unroll
    for (int t = 0; t < 8; t++) {
        float a0 = bi0, a1 = bi1;
#pragma unroll
        for (int kk = 0; kk < KW_; kk++) {
            a0 += in0[t + kk] * w0[kk];
            a1 += in1[t + kk] * w1[kk];
        }
        float s0 = 1.f / (1.f + __expf(1.f - a0));
        float s1 = 1.f / (1.f + __expf(1.f - a1));
        u32 o = (u32)f2b(a0 * s0) | ((u32)f2b(a1 * s1) << 16);
        *(u32 *)&cd[(t0 + t) * 2048 + b * 512 + c0] = o;
    }
}

// BasicNorm -> FLOAT32 output. One wave per row.
__global__ __launch_bounds__(256) void norm_k(const float *xr, const float *epsp, float *out) {
    int wv = threadIdx.x >> 6, ln = threadIdx.x & 63;
    long long row = blockIdx.x * 4 + wv;
    const float *x = xr + row * E_;
    float vals[8], ss = 0.f;
#pragma unroll
    for (int i = 0; i < 8; i++) {
        vals[i] = x[ln + (i << 6)];
        ss += vals[i] * vals[i];
    }
#pragma unroll
    for (int m = 32; m; m >>= 1) ss += __shfl_xor(ss, m, 64);
    float sc = rsqrtf(ss * (1.f / (float)E_) + __expf(epsp[0]));
    float *o = out + row * E_;
#pragma unroll
    for (int i = 0; i < 8; i++) o[ln + (i << 6)] = vals[i] * sc;
}

// ---------------- host ------------------------------------------------------------

extern "C" void kernel_launch(void *const *d_in, const int *in_sizes, int n_in,
                              void *d_out, int out_size, void *d_ws, size_t ws_size,
                              hipStream_t stream) {
    const size_t MB = (size_t)1 << 20;
    static const long long EXPECT[24] = {
        2097152, 1048064, 786432, 1536, 262144, 512, 262144, 512, 512,
        1048576, 2048, 1048576, 512, 1048576, 2048, 1048576, 512,
        524288, 1024, 15872, 512, 262144, 512, 1};
    const size_t NEED = 93 * MB;

    float code = 0.f;
    if (n_in != 24) {
        code = 1000.f + (float)n_in;
    } else {
        for (int i = 0; i < 24; i++) {
            if ((long long)in_sizes[i] != EXPECT[i]) { code = 2000.f + 64.f * i; break; }
        }
    }
    if (code == 0.f && out_size != 2097152) code = 3000.f;
    if (code == 0.f && ws_size < NEED) code = 5000.f + (float)(ws_size / MB);
    if (code != 0.f) {
        long long n = (long long)out_size;
        fill_k<<<dim3((unsigned)((n + 255) / 256)), dim3(256), 0, stream>>>((float *)d_out, n, code);
        return;
    }

    char *w = (char *)d_ws;
    int *flag = (int *)(w + 0);
    u16 *cv = (u16 *)(w + 1 * MB);
    float *xr = (float *)(w + 21 * MB);
    u16 *xb = (u16 *)(w + 29 * MB);
    u16 *h1 = (u16 *)(w + 33 * MB);
    u16 *vbuf = (u16 *)(w + 49 * MB);   // 4 MB compact V (was qkv/y1 slot)
    u16 *pp = (u16 *)(w + 61 * MB);
    u16 *pph = (u16 *)(w + 63 * MB);
    u16 *QU = (u16 *)(w + 65 * MB);
    u16 *QV = (u16 *)(w + 69 * MB);
    u16 *KH = (u16 *)(w + 73 * MB);
    u16 *VT = (u16 *)(w + 77 * MB);
    u16 *attno = (u16 *)(w + 81 * MB);
    u16 *ch = (u16 *)(w + 85 * MB);
    u16 *cd = (u16 *)(w + 89 * MB);

    detect_k<<<dim3(1), dim3(256), 0, stream>>>((const u16 *)d_in[0], flag);
    CVT c;
    c.pre[0] = 0;
    for (int i = 0; i < 24; i++) {
        c.in[i] = d_in[i];
        c.pre[i + 1] = c.pre[i] + in_sizes[i];
    }
    long long total = c.pre[24];
    convert_k<<<dim3((unsigned)((total + 255) / 256)), dim3(256), 0, stream>>>(c, cv, flag, total);

    const u16 *src = cv + c.pre[0];
    const u16 *pos_emb = cv + c.pre[1];
    const u16 *w_qkv = cv + c.pre[2];
    const u16 *b_qkv = cv + c.pre[3];
    const u16 *w_o = cv + c.pre[4];
    const u16 *b_o = cv + c.pre[5];
    const u16 *w_pos = cv + c.pre[6];
    const u16 *u_bias = cv + c.pre[7];
    const u16 *v_bias = cv + c.pre[8];
    const u16 *ffm_w1 = cv + c.pre[9];
    const u16 *ffm_b1 = cv + c.pre[10];
    const u16 *ffm_w2 = cv + c.pre[11];
    const u16 *ffm_b2 = cv + c.pre[12];
    const u16 *ff_w1 = cv + c.pre[13];
    const u16 *ff_b1 = cv + c.pre[14];
    const u16 *ff_w2 = cv + c.pre[15];
    const u16 *ff_b2 = cv + c.pre[16];
    const u16 *pw1_w = cv + c.pre[17];
    const u16 *pw1_b = cv + c.pre[18];
    const u16 *dw_w = cv + c.pre[19];
    const u16 *dw_b = cv + c.pre[20];
    const u16 *pw2_w = cv + c.pre[21];
    const u16 *pw2_b = cv + c.pre[22];

    auto mk = [](const void *A, int lda, const void *B, int ldb, void *C, int ldc,
                 const void *bias, int M, int N, int K, int mode) {
        GP p;
        memset(&p, 0, sizeof(p));
        p.A = (const u16 *)A; p.B = (const u16 *)B; p.C = (u16 *)C; p.bias = (const u16 *)bias;
        p.M = M; p.N = N; p.K = K; p.lda = lda; p.ldb = ldb; p.ldc = ldc; p.mode = mode;
        p.qscale = 1.f;
        return p;
    };
    auto launch = [&](GP p) {
        dim3 g((p.N + 63) / 64, (p.M + 63) / 64, 1);
        gemm_nt<<<g, dim3(256), 0, stream>>>(p);
    };
    auto launch128 = [&](GP p) {
        dim3 g(p.N >> 7, p.M >> 7, 1);
        gemm_nt128<<<g, dim3(256), 0, stream>>>(p);
    };

    const int M = T_ * B_;  // 4096

    // ---- macaron FFN: x1 = src + W2 @ dswish(W1 @ src + b1) + b2
    { GP p = mk(src, E_, ffm_w1, E_, h1, DFF_, ffm_b1, M, DFF_, E_, 1); launch128(p); }
    { GP p = mk(h1, DFF_, ffm_w2, DFF_, nullptr, E_, ffm_b2, M, E_, DFF_, 2);
      p.resin = d_in[0]; p.resin_f32 = 1; p.xr = xr; p.xb = xb; launch128(p); }

    // ---- attention projections (qkv GEMM fuses repack into epilogue)
    { GP p = mk(xb, E_, w_qkv, E_, nullptr, 0, b_qkv, M, 3 * E_, E_, 4);
      p.u2 = u_bias; p.v2 = v_bias; p.qu = QU; p.qv = QV; p.kh = KH; p.vb = vbuf;
      launch128(p); }
    { GP p = mk(pos_emb, E_, w_pos, E_, pp, E_, nullptr, 2 * T_ - 1, E_, E_, 0); launch(p); }
    repack_pos_k<<<dim3(4096), dim3(256), 0, stream>>>(pp, pph);
    transpose_v_k<<<dim3(16, 32), dim3(256), 0, stream>>>(vbuf, VT);

    // ---- flash attention (no S materialization)
    {
        FK f;
        f.QU = QU; f.QV = QV; f.KH = KH; f.PPH = pph; f.VT = VT; f.attno = attno;
        flash_k<<<dim3(16, 32), dim3(256), 0, stream>>>(f);
    }

    // ---- out projection + residual -> x2
    { GP p = mk(attno, E_, w_o, E_, nullptr, E_, b_o, M, E_, E_, 2);
      p.resin = xr; p.resin_f32 = 1; p.xr = xr; p.xb = xb; launch(p); }

    // ---- conv module (pw1 fuses GLU into epilogue; writes ch directly)
    { GP p = mk(xb, E_, pw1_w, E_, ch, E_, pw1_b, M, E_, E_, 3); launch(p); }
    dwconv_k<<<dim3(512), dim3(256), 0, stream>>>(ch, dw_w, dw_b, cd);
    { GP p = mk(cd, E_, pw2_w, E_, nullptr, E_, pw2_b, M, E_, E_, 2);
      p.resin = xr; p.resin_f32 = 1; p.xr = xr; p.xb = xb; launch(p); }

    // ---- second FFN
    { GP p = mk(xb, E_, ff_w1, E_, h1, DFF_, ff_b1, M, DFF_, E_, 1); launch128(p); }
    { GP p = mk(h1, DFF_, ff_w2, DFF_, nullptr, E_, ff_b2, M, E_, DFF_, 2);
      p.resin = xr; p.resin_f32 = 1; p.xr = xr; p.xb = nullptr; launch128(p); }

    // ---- final BasicNorm -> d_out (FLOAT32)
    norm_k<<<dim3(M / 4), dim3(256), 0, stream>>>(xr, (const float *)d_in[23], (float *)d_out);
}